// Round 5
// baseline (2668.990 us; speedup 1.0000x reference)
//
#include <hip/hip_runtime.h>
#include <hip/hip_bf16.h>
#include <hip/hip_fp16.h>

// LSTMNet: B=512, T=1024, IN=32, H=128 (gates G=512), 2 layers, head 128->256->32 (CELU).
// Round 4:
//  - xg preacts stored fp16 (halves gemm write + scan read traffic).
//  - lstm scan: single barrier/step. MFMA D-frag lanes 0-15 hold all 4 gates x 4
//    batches for channel ch=w*16+lr -> in-lane cell update (no pre[] scatter, no 2nd
//    barrier). h double-buffered in 2x1KB LDS, swizzle ^(r<<6) (2-way = free). xg
//    prefetched 1 step ahead (ping-pong regs). Wf pinned with IN-LOOP asm (round-3
//    lesson: a one-time pin doesn't stop rematerialization; VGPR=60 proved reload).
//  - G0+G1 fused in one launch (grid.z); all f32->bf16 converts folded into consumers
//    (gemm stages W and x from fp32; scan cvts Whh at prologue). No cvt kernels.

#define DEV __device__ __forceinline__

typedef float f32x4 __attribute__((ext_vector_type(4)));
typedef short bf16x8 __attribute__((ext_vector_type(8)));
typedef unsigned short ushort_t;

DEV float sigm(float x) { return 1.f / (1.f + __expf(-x)); }
DEV float tanhfast(float x) { float e = __expf(2.f * x); return (e - 1.f) / (e + 1.f); }
DEV float celu1(float x) { return x > 0.f ? x : (__expf(x) - 1.f); }

DEV short f2bf(float f) {
    __hip_bfloat16 h = __float2bfloat16(f);   // RNE
    return *reinterpret_cast<short*>(&h);
}
DEV ushort_t f2h(float f) {
    __half h = __float2half(f);               // RNE
    return *reinterpret_cast<ushort_t*>(&h);
}
DEV float h2f(ushort_t u) {
    __half h;
    *reinterpret_cast<ushort_t*>(&h) = u;
    return __half2float(h);
}

// ---------------- bf16 MFMA input-projection GEMM body ------------------------------
// C[r][g] = fp16( sum_k A[r][k]*W[g][k] + bA[g] + bB[g] ), C [*, 512] fp16.
// Tile 128(M) x 128(N) x full-K, 256 threads (4 waves). W staged from fp32 (cvt bf16).
// XMAP: A = x fp32 (B,1024,32), row r -> (b=r/TC, t=t0+r%TC), cvt bf16 in staging.
// else: A = h0c bf16 contiguous [r][128].
template<int K, bool XMAP>
DEV void gemm_body(char* lds, const void* Av, const float* __restrict__ Wg,
                   const float* __restrict__ bA, const float* __restrict__ bB,
                   ushort_t* __restrict__ C, int t0, int TC, int bx, int by)
{
    constexpr int SWB = K * 2;                // LDS row bytes
    constexpr int SM  = (K == 32) ? 3 : 7;    // swizzle mask
    char* As = lds;
    char* Ws = lds + 128 * SWB;

    const int tid = threadIdx.x;
    const int r0 = bx * 128;
    const int g0 = by * 128;
    const int lane = tid & 63, w = tid >> 6;
    const int lr = lane & 15, kg = lane >> 4;

    constexpr int UPR = SWB / 16;
    constexpr int NIT = 128 * UPR / 256;
#pragma unroll
    for (int e = 0; e < NIT; e++) {
        int idx = tid + e * 256;
        int row = idx / UPR;
        int kb  = (idx - row * UPR) * 16;
        int dst = row * SWB + (kb ^ ((row & SM) << 4));
        int ke  = kb >> 1;                    // element offset
        bf16x8 av;
        if (XMAP) {
            const float* A = (const float*)Av;
            int r = r0 + row;
            int b = r / TC, tt = r - b * TC;
            const float* p = A + ((size_t)b * 1024 + (size_t)(t0 + tt)) * 32 + ke;
            float4 f0 = *(const float4*)p, f1 = *(const float4*)(p + 4);
            av[0] = f2bf(f0.x); av[1] = f2bf(f0.y); av[2] = f2bf(f0.z); av[3] = f2bf(f0.w);
            av[4] = f2bf(f1.x); av[5] = f2bf(f1.y); av[6] = f2bf(f1.z); av[7] = f2bf(f1.w);
        } else {
            const ushort_t* A = (const ushort_t*)Av;
            av = *(const bf16x8*)(A + (size_t)(r0 + row) * K + ke);
        }
        *(bf16x8*)(As + dst) = av;
        {
            const float* p = Wg + (size_t)(g0 + row) * K + ke;
            float4 f0 = *(const float4*)p, f1 = *(const float4*)(p + 4);
            bf16x8 wv;
            wv[0] = f2bf(f0.x); wv[1] = f2bf(f0.y); wv[2] = f2bf(f0.z); wv[3] = f2bf(f0.w);
            wv[4] = f2bf(f1.x); wv[5] = f2bf(f1.y); wv[6] = f2bf(f1.z); wv[7] = f2bf(f1.w);
            *(bf16x8*)(Ws + dst) = wv;
        }
    }
    __syncthreads();

    f32x4 acc[2][8];
#pragma unroll
    for (int mi = 0; mi < 2; mi++)
#pragma unroll
        for (int n = 0; n < 8; n++) acc[mi][n] = (f32x4){0.f, 0.f, 0.f, 0.f};

    const int m0 = w * 32;
#pragma unroll
    for (int ks = 0; ks < K / 32; ks++) {
        const int kb = ks * 64 + kg * 16;
        const int ra0 = m0 + lr, ra1 = m0 + 16 + lr;
        bf16x8 a0 = *(const bf16x8*)(As + ra0 * SWB + (kb ^ ((ra0 & SM) << 4)));
        bf16x8 a1 = *(const bf16x8*)(As + ra1 * SWB + (kb ^ ((ra1 & SM) << 4)));
#pragma unroll
        for (int n = 0; n < 8; n++) {
            int wr = n * 16 + lr;
            bf16x8 bw = *(const bf16x8*)(Ws + wr * SWB + (kb ^ ((wr & SM) << 4)));
            acc[0][n] = __builtin_amdgcn_mfma_f32_16x16x32_bf16(a0, bw, acc[0][n], 0, 0, 0);
            acc[1][n] = __builtin_amdgcn_mfma_f32_16x16x32_bf16(a1, bw, acc[1][n], 0, 0, 0);
        }
    }

    // epilogue: D col = lane&15 (gate), row = kg*4 + reg; store fp16
#pragma unroll
    for (int n = 0; n < 8; n++) {
        int g = g0 + n * 16 + lr;
        float bias = bA[g] + bB[g];
#pragma unroll
        for (int mi = 0; mi < 2; mi++) {
            int rrow = r0 + m0 + mi * 16 + kg * 4;
#pragma unroll
            for (int rr = 0; rr < 4; rr++)
                C[(size_t)(rrow + rr) * 512 + g] = f2h(acc[mi][n][rr] + bias);
        }
    }
}

// MODE 0: z=0 -> L1 gemm, z=1 -> L0 gemm.  MODE 1: L0 only.  MODE 2: L1 only.
template<int MODE>
__global__ __launch_bounds__(256, 2)
void gemm_pair(const float* __restrict__ x, const float* __restrict__ wih0,
               const float* __restrict__ bih0, const float* __restrict__ bhh0,
               ushort_t* __restrict__ xg0, int t0,
               const ushort_t* __restrict__ h0c, const float* __restrict__ wih1,
               const float* __restrict__ bih1, const float* __restrict__ bhh1,
               ushort_t* __restrict__ xg1, int TC)
{
    __shared__ char lds[65536];
    const int path = (MODE == 0) ? (int)blockIdx.z : ((MODE == 1) ? 0 : 1);
    if (path == 0)
        gemm_body<32,  true >(lds, x,   wih0, bih0, bhh0, xg0, t0, TC,
                              blockIdx.x, blockIdx.y);
    else
        gemm_body<128, false>(lds, h0c, wih1, bih1, bhh1, xg1, 0, TC,
                              blockIdx.x, blockIdx.y);
}

// ---------------- MFMA LSTM scan -----------------------------------------------------
// Block: 4 batch rows, 512 threads (8 waves). Wave w owns channels w*16..w*16+15 for
// all 4 gate types. Lane layout: lr=lane&15, kg=lane>>4. A-frag row = lr&3 (batch,
// 4x duplicated -> D rows 0-3 valid in lanes 0-15 regs 0-3). Lanes 0-15 do the cell
// update in-lane. One barrier per step; h_lds double-buffered.
template<int WRITE_H>
DEV void scan_body(const ushort_t* __restrict__ xg, const float* __restrict__ whh,
                   float* __restrict__ hs, float* __restrict__ cs,
                   ushort_t* __restrict__ hout, int TC, int blk)
{
    __shared__ char hb[2][1024];               // h bf16: byte r*256 + ((ch*2)^(r<<6))

    const int t    = threadIdx.x;
    const int lane = t & 63;
    const int w    = t >> 6;
    const int b0   = blk * 4;
    const int lr   = lane & 15, kg = lane >> 4;
    const int ch   = w * 16 + lr;
    const int arow = lr & 3;

    // Whh fp32 -> bf16 B-fragments (once)
    bf16x8 Wf[4][4];
#pragma unroll
    for (int q = 0; q < 4; q++)
#pragma unroll
        for (int kt = 0; kt < 4; kt++) {
            const float* p = whh + (size_t)(q * 128 + ch) * 128 + kt * 32 + kg * 8;
            bf16x8 v;
#pragma unroll
            for (int j = 0; j < 8; j++) v[j] = f2bf(p[j]);
            Wf[q][kt] = v;
        }

    float cst[4] = {0.f, 0.f, 0.f, 0.f};
    float hk[4]  = {0.f, 0.f, 0.f, 0.f};
    if (lane < 16) {
#pragma unroll
        for (int r = 0; r < 4; r++) {
            hk[r]  = hs[(size_t)(b0 + r) * 128 + ch];
            cst[r] = cs[(size_t)(b0 + r) * 128 + ch];
            *(short*)(&hb[0][0] + r * 256 + ((ch * 2) ^ (r << 6))) = f2bf(hk[r]);
        }
    }
    __syncthreads();

    ushort_t xpA[16], xpB[16];                 // [r*4+q] ping-pong prefetch
    if (lane < 16) {
#pragma unroll
        for (int r = 0; r < 4; r++)
#pragma unroll
            for (int q = 0; q < 4; q++)
                xpA[r * 4 + q] = xg[(size_t)(b0 + r) * TC * 512 + q * 128 + ch];
    }

    auto step = [&](int tt, int rb, ushort_t (&xu)[16], ushort_t (&xl)[16], bool pre) {
        // in-loop pin: asm "writes" Wf -> compiler cannot rematerialize from memory
        asm volatile("" : "+v"(Wf[0][0]), "+v"(Wf[0][1]), "+v"(Wf[0][2]), "+v"(Wf[0][3]),
                          "+v"(Wf[1][0]), "+v"(Wf[1][1]), "+v"(Wf[1][2]), "+v"(Wf[1][3]),
                          "+v"(Wf[2][0]), "+v"(Wf[2][1]), "+v"(Wf[2][2]), "+v"(Wf[2][3]),
                          "+v"(Wf[3][0]), "+v"(Wf[3][1]), "+v"(Wf[3][2]), "+v"(Wf[3][3]));
        const char* hbase = hb[rb];
        bf16x8 Af[4];
#pragma unroll
        for (int kt = 0; kt < 4; kt++)
            Af[kt] = *(const bf16x8*)(hbase + arow * 256
                                      + ((kt * 64 + kg * 16) ^ (arow << 6)));
        if (pre && lane < 16) {                // prefetch next step's xg
#pragma unroll
            for (int r = 0; r < 4; r++)
#pragma unroll
                for (int q = 0; q < 4; q++)
                    xl[r * 4 + q] = xg[((size_t)(b0 + r) * TC + (tt + 1)) * 512
                                       + q * 128 + ch];
        }
        f32x4 acc[4];
#pragma unroll
        for (int q = 0; q < 4; q++) {
            f32x4 a = {0.f, 0.f, 0.f, 0.f};
#pragma unroll
            for (int kt = 0; kt < 4; kt++)
                a = __builtin_amdgcn_mfma_f32_16x16x32_bf16(Af[kt], Wf[q][kt], a, 0, 0, 0);
            acc[q] = a;
        }
        if (lane < 16) {
            char* hw = hb[rb ^ 1];
#pragma unroll
            for (int r = 0; r < 4; r++) {
                float pi = acc[0][r] + h2f(xu[r * 4 + 0]);
                float pf = acc[1][r] + h2f(xu[r * 4 + 1]);
                float pg = acc[2][r] + h2f(xu[r * 4 + 2]);
                float po = acc[3][r] + h2f(xu[r * 4 + 3]);
                float iv = sigm(pi), fv = sigm(pf), gv = tanhfast(pg), ov = sigm(po);
                cst[r] = fv * cst[r] + iv * gv;
                float hv = ov * tanhfast(cst[r]);
                hk[r] = hv;
                short hb16 = f2bf(hv);
                *(short*)(hw + r * 256 + ((ch * 2) ^ (r << 6))) = hb16;
                if (WRITE_H)
                    hout[((size_t)(b0 + r) * TC + tt) * 128 + ch] = (ushort_t)hb16;
            }
        }
        __syncthreads();
    };

    for (int tt = 0; tt < TC; tt += 2) {
        step(tt,     0, xpA, xpB, true);
        step(tt + 1, 1, xpB, xpA, (tt + 2) < TC);
    }

    if (lane < 16) {
#pragma unroll
        for (int r = 0; r < 4; r++) {
            hs[(size_t)(b0 + r) * 128 + ch] = hk[r];
            cs[(size_t)(b0 + r) * 128 + ch] = cst[r];
        }
    }
}

template<int WRITE_H>
__global__ __launch_bounds__(512, 2)
void lstm_scan(const ushort_t* __restrict__ xg, const float* __restrict__ whh,
               float* __restrict__ hs, float* __restrict__ cs,
               ushort_t* __restrict__ hout, int TC)
{
    scan_body<WRITE_H>(xg, whh, hs, cs, hout, TC, blockIdx.x);
}

// blocks 0-127: layer-0 chunk c (writes h0c); 128-255: layer-1 chunk c-1
__global__ __launch_bounds__(512, 2)
void lstm_scan_dual(const ushort_t* __restrict__ xg0, const float* __restrict__ whh0,
                    float* __restrict__ h0s, float* __restrict__ c0s,
                    ushort_t* __restrict__ hout,
                    const ushort_t* __restrict__ xg1, const float* __restrict__ whh1,
                    float* __restrict__ h1s, float* __restrict__ c1s, int TC)
{
    if (blockIdx.x < 128)
        scan_body<1>(xg0, whh0, h0s, c0s, hout, TC, blockIdx.x);
    else
        scan_body<0>(xg1, whh1, h1s, c1s, nullptr, TC, blockIdx.x - 128);
}

// ---------------- head ---------------------------------------------------------------
__global__ __launch_bounds__(256, 2)
void head_k(const float* __restrict__ h1s, const float* __restrict__ W1,
            const float* __restrict__ b1, const float* __restrict__ W2,
            const float* __restrict__ b2, float* __restrict__ out)
{
    __shared__ float hrow[128];
    __shared__ float y1[256];
    const int b = blockIdx.x;
    const int tid = threadIdx.x;
    if (tid < 128) hrow[tid] = h1s[(size_t)b * 128 + tid];
    __syncthreads();
    {
        float acc = b1[tid];
        const float4* wp = (const float4*)(W1 + (size_t)tid * 128);
        const float4* hp = (const float4*)hrow;
#pragma unroll 8
        for (int q = 0; q < 32; q++) {
            float4 wv = wp[q]; float4 hv = hp[q];
            acc += wv.x * hv.x + wv.y * hv.y + wv.z * hv.z + wv.w * hv.w;
        }
        y1[tid] = celu1(acc);
    }
    __syncthreads();
    if (tid < 32) {
        float acc = b2[tid];
        const float4* wp = (const float4*)(W2 + (size_t)tid * 256);
        const float4* yp = (const float4*)y1;
#pragma unroll 8
        for (int q = 0; q < 64; q++) {
            float4 wv = wp[q]; float4 yv = yp[q];
            acc += wv.x * yv.x + wv.y * yv.y + wv.z * yv.z + wv.w * yv.w;
        }
        out[(size_t)b * 32 + tid] = celu1(acc);
    }
}

extern "C" void kernel_launch(void* const* d_in, const int* in_sizes, int n_in,
                              void* d_out, int out_size, void* d_ws, size_t ws_size,
                              hipStream_t stream)
{
    const float* x    = (const float*)d_in[0];
    const float* Wih0 = (const float*)d_in[1];
    const float* Whh0 = (const float*)d_in[2];
    const float* bih0 = (const float*)d_in[3];
    const float* bhh0 = (const float*)d_in[4];
    const float* Wih1 = (const float*)d_in[5];
    const float* Whh1 = (const float*)d_in[6];
    const float* bih1 = (const float*)d_in[7];
    const float* bhh1 = (const float*)d_in[8];
    const float* W1   = (const float*)d_in[9];
    const float* b1   = (const float*)d_in[10];
    const float* W2   = (const float*)d_in[11];
    const float* b2   = (const float*)d_in[12];
    float* out = (float*)d_out;

    // workspace: xg0, xg1 (fp16), h0c (bf16), 4 fp32 state arrays
    int TC = 128;
    while (TC > 8) {
        size_t need = 2ull * 512 * TC * 512 * 2 + (size_t)512 * TC * 128 * 2
                    + 4ull * 512 * 128 * 4;
        if (need <= ws_size) break;
        TC >>= 1;
    }

    ushort_t* xg0 = (ushort_t*)d_ws;
    ushort_t* xg1 = xg0 + (size_t)512 * TC * 512;
    ushort_t* h0c = xg1 + (size_t)512 * TC * 512;
    float* st  = (float*)(h0c + (size_t)512 * TC * 128);
    float* h0s = st;
    float* c0s = st + 512 * 128;
    float* h1s = st + 2 * 512 * 128;
    float* c1s = st + 3 * 512 * 128;

    hipMemsetAsync(st, 0, (size_t)4 * 512 * 128 * 4, stream);          // h,c = 0
    hipMemsetAsync(out + 16384, 0, (size_t)131072 * 4, stream);        // hidden_init

    const int NC = 1024 / TC;
    dim3 g1((unsigned)(512 * TC / 128), 4, 1);
    dim3 g2((unsigned)(512 * TC / 128), 4, 2);

    gemm_pair<1><<<g1, 256, 0, stream>>>(x, Wih0, bih0, bhh0, xg0, 0,
                                         nullptr, Wih1, bih1, bhh1, xg1, TC);
    lstm_scan<1><<<128, 512, 0, stream>>>(xg0, Whh0, h0s, c0s, h0c, TC);
    for (int c = 1; c < NC; c++) {
        gemm_pair<0><<<g2, 256, 0, stream>>>(x, Wih0, bih0, bhh0, xg0, c * TC,
                                             h0c, Wih1, bih1, bhh1, xg1, TC);
        lstm_scan_dual<<<256, 512, 0, stream>>>(xg0, Whh0, h0s, c0s, h0c,
                                                xg1, Whh1, h1s, c1s, TC);
    }
    gemm_pair<2><<<g1, 256, 0, stream>>>(x, Wih0, bih0, bhh0, xg0, 0,
                                         h0c, Wih1, bih1, bhh1, xg1, TC);
    lstm_scan<0><<<128, 512, 0, stream>>>(xg1, Whh1, h1s, c1s, nullptr, TC);

    head_k<<<512, 256, 0, stream>>>(h1s, W1, b1, W2, b2, out);
}

// Round 7
// 1456.524 us; speedup vs baseline: 1.8324x; 1.8324x over previous
//
#include <hip/hip_runtime.h>
#include <hip/hip_bf16.h>
#include <hip/hip_fp16.h>

// LSTMNet: B=512, T=1024, IN=32, H=128 (gates G=512), 2 layers, head 128->256->32 (CELU).
// Round 6 = round 5 resubmitted verbatim (round-5 bench died on GPUAcquisitionTimeout;
// no counters, so no change is justified).
// Round 5: revert scan to the round-3 structure (proven 67us dual) after round-4's
// lane-concentration regression (263us: update+loads on lanes 0-15 = 4x issue count,
// 2-byte uncoalesced loads). Keep from round 4: fp16 xg (absmax-neutral, halves
// traffic), in-loop asm pin of Whh fragments (VGPR 60->84 proved mechanism), fused
// gemm_pair with folded f32->bf16 converts.
// Scan: 4 batch rows/block, 512 thr. Wave w owns ch w*16..w*16+15, all 4 gate types.
// Per step: all threads read 4 fp16 xg (coalesced), MFMA 4x4 chain (Wf pinned),
// lanes kg==0 scatter preacts to pre[], barrier, each thread updates 1 gate-quad
// (full-wave transcendentals), write h bf16 swizzled + hout, barrier.

#define DEV __device__ __forceinline__

typedef float f32x4 __attribute__((ext_vector_type(4)));
typedef short bf16x8 __attribute__((ext_vector_type(8)));
typedef unsigned short ushort_t;

DEV float sigm(float x) { return 1.f / (1.f + __expf(-x)); }
DEV float tanhfast(float x) { float e = __expf(2.f * x); return (e - 1.f) / (e + 1.f); }
DEV float celu1(float x) { return x > 0.f ? x : (__expf(x) - 1.f); }

DEV short f2bf(float f) {
    __hip_bfloat16 h = __float2bfloat16(f);   // RNE
    return *reinterpret_cast<short*>(&h);
}
DEV ushort_t f2h(float f) {
    __half h = __float2half(f);               // RNE
    return *reinterpret_cast<ushort_t*>(&h);
}
DEV float h2f(ushort_t u) {
    __half h;
    *reinterpret_cast<ushort_t*>(&h) = u;
    return __half2float(h);
}

// ---------------- bf16 MFMA input-projection GEMM body ------------------------------
// C[r][g] = fp16( sum_k A[r][k]*W[g][k] + bA[g] + bB[g] ), C [*, 512] fp16.
// Tile 128(M) x 128(N) x full-K, 256 threads (4 waves). W staged from fp32 (cvt bf16).
// XMAP: A = x fp32 (B,1024,32), row r -> (b=r/TC, t=t0+r%TC), cvt bf16 in staging.
// else: A = h0c bf16 contiguous [r][128].
template<int K, bool XMAP>
DEV void gemm_body(char* lds, const void* Av, const float* __restrict__ Wg,
                   const float* __restrict__ bA, const float* __restrict__ bB,
                   ushort_t* __restrict__ C, int t0, int TC, int bx, int by)
{
    constexpr int SWB = K * 2;                // LDS row bytes
    constexpr int SM  = (K == 32) ? 3 : 7;    // swizzle mask
    char* As = lds;
    char* Ws = lds + 128 * SWB;

    const int tid = threadIdx.x;
    const int r0 = bx * 128;
    const int g0 = by * 128;
    const int lane = tid & 63, w = tid >> 6;
    const int lr = lane & 15, kg = lane >> 4;

    constexpr int UPR = SWB / 16;
    constexpr int NIT = 128 * UPR / 256;
#pragma unroll
    for (int e = 0; e < NIT; e++) {
        int idx = tid + e * 256;
        int row = idx / UPR;
        int kb  = (idx - row * UPR) * 16;
        int dst = row * SWB + (kb ^ ((row & SM) << 4));
        int ke  = kb >> 1;                    // element offset
        bf16x8 av;
        if (XMAP) {
            const float* A = (const float*)Av;
            int r = r0 + row;
            int b = r / TC, tt = r - b * TC;
            const float* p = A + ((size_t)b * 1024 + (size_t)(t0 + tt)) * 32 + ke;
            float4 f0 = *(const float4*)p, f1 = *(const float4*)(p + 4);
            av[0] = f2bf(f0.x); av[1] = f2bf(f0.y); av[2] = f2bf(f0.z); av[3] = f2bf(f0.w);
            av[4] = f2bf(f1.x); av[5] = f2bf(f1.y); av[6] = f2bf(f1.z); av[7] = f2bf(f1.w);
        } else {
            const ushort_t* A = (const ushort_t*)Av;
            av = *(const bf16x8*)(A + (size_t)(r0 + row) * K + ke);
        }
        *(bf16x8*)(As + dst) = av;
        {
            const float* p = Wg + (size_t)(g0 + row) * K + ke;
            float4 f0 = *(const float4*)p, f1 = *(const float4*)(p + 4);
            bf16x8 wv;
            wv[0] = f2bf(f0.x); wv[1] = f2bf(f0.y); wv[2] = f2bf(f0.z); wv[3] = f2bf(f0.w);
            wv[4] = f2bf(f1.x); wv[5] = f2bf(f1.y); wv[6] = f2bf(f1.z); wv[7] = f2bf(f1.w);
            *(bf16x8*)(Ws + dst) = wv;
        }
    }
    __syncthreads();

    f32x4 acc[2][8];
#pragma unroll
    for (int mi = 0; mi < 2; mi++)
#pragma unroll
        for (int n = 0; n < 8; n++) acc[mi][n] = (f32x4){0.f, 0.f, 0.f, 0.f};

    const int m0 = w * 32;
#pragma unroll
    for (int ks = 0; ks < K / 32; ks++) {
        const int kb = ks * 64 + kg * 16;
        const int ra0 = m0 + lr, ra1 = m0 + 16 + lr;
        bf16x8 a0 = *(const bf16x8*)(As + ra0 * SWB + (kb ^ ((ra0 & SM) << 4)));
        bf16x8 a1 = *(const bf16x8*)(As + ra1 * SWB + (kb ^ ((ra1 & SM) << 4)));
#pragma unroll
        for (int n = 0; n < 8; n++) {
            int wr = n * 16 + lr;
            bf16x8 bw = *(const bf16x8*)(Ws + wr * SWB + (kb ^ ((wr & SM) << 4)));
            acc[0][n] = __builtin_amdgcn_mfma_f32_16x16x32_bf16(a0, bw, acc[0][n], 0, 0, 0);
            acc[1][n] = __builtin_amdgcn_mfma_f32_16x16x32_bf16(a1, bw, acc[1][n], 0, 0, 0);
        }
    }

    // epilogue: D col = lane&15 (gate), row = kg*4 + reg; store fp16
#pragma unroll
    for (int n = 0; n < 8; n++) {
        int g = g0 + n * 16 + lr;
        float bias = bA[g] + bB[g];
#pragma unroll
        for (int mi = 0; mi < 2; mi++) {
            int rrow = r0 + m0 + mi * 16 + kg * 4;
#pragma unroll
            for (int rr = 0; rr < 4; rr++)
                C[(size_t)(rrow + rr) * 512 + g] = f2h(acc[mi][n][rr] + bias);
        }
    }
}

// MODE 0: z=0 -> L1 gemm, z=1 -> L0 gemm.  MODE 1: L0 only.  MODE 2: L1 only.
template<int MODE>
__global__ __launch_bounds__(256, 2)
void gemm_pair(const float* __restrict__ x, const float* __restrict__ wih0,
               const float* __restrict__ bih0, const float* __restrict__ bhh0,
               ushort_t* __restrict__ xg0, int t0,
               const ushort_t* __restrict__ h0c, const float* __restrict__ wih1,
               const float* __restrict__ bih1, const float* __restrict__ bhh1,
               ushort_t* __restrict__ xg1, int TC)
{
    __shared__ char lds[65536];
    const int path = (MODE == 0) ? (int)blockIdx.z : ((MODE == 1) ? 0 : 1);
    if (path == 0)
        gemm_body<32,  true >(lds, x,   wih0, bih0, bhh0, xg0, t0, TC,
                              blockIdx.x, blockIdx.y);
    else
        gemm_body<128, false>(lds, h0c, wih1, bih1, bhh1, xg1, 0, TC,
                              blockIdx.x, blockIdx.y);
}

// ---------------- MFMA LSTM scan (round-3 structure) ---------------------------------
// MFMA D[m][n]: m = kg*4+reg (batches 0-3 real), n = lr (channel in wave's tile).
// A-frag: h[m=lr][k=kg*8+j] bf16 (rows 4-15 zeroed once). Whh fragments pinned in-loop.
template<int WRITE_H>
DEV void scan_body(const ushort_t* __restrict__ xg, const float* __restrict__ whh,
                   float* __restrict__ hs, float* __restrict__ cs,
                   ushort_t* __restrict__ hout, int TC, int blk)
{
    __shared__ short h_lds[16 * 128];          // bf16 bits, swizzled ^((m&7)<<4)
    __shared__ float pre[4 * 4 * 128];         // [q][m][ch]

    const int t    = threadIdx.x;
    const int lane = t & 63;
    const int w    = t >> 6;
    const int b0   = blk * 4;
    const int um   = t >> 7;                   // update: batch row 0..3
    const int uch  = t & 127;                  // update: channel 0..127
    const int lr   = lane & 15, kg = lane >> 4;

    // Whh fp32 -> bf16 B-fragments (once)
    bf16x8 Wf[4][4];
#pragma unroll
    for (int q = 0; q < 4; q++)
#pragma unroll
        for (int kt = 0; kt < 4; kt++) {
            const float* p = whh + (size_t)(q * 128 + w * 16 + lr) * 128 + kt * 32 + kg * 8;
            bf16x8 v;
#pragma unroll
            for (int j = 0; j < 8; j++) v[j] = f2bf(p[j]);
            Wf[q][kt] = v;
        }

    float c_reg  = cs[(size_t)(b0 + um) * 128 + uch];
    float h_keep = hs[(size_t)(b0 + um) * 128 + uch];
    *(short*)((char*)h_lds + um * 256 + ((uch * 2) ^ (um << 4))) = f2bf(h_keep);
    if (t < 384)   // zero rows 4..15 (A-tile padding; swizzle is a bijection per row)
        *(unsigned long long*)((char*)h_lds + 4 * 256 + t * 8) = 0ull;
    __syncthreads();

    const int abase = lr * 256;
    const int aswz  = (lr & 7) << 4;
    const int akoff = kg * 16;

    for (int tt = 0; tt < TC; tt++) {
        // this step's input preacts: full-wave coalesced fp16 loads
        const size_t xr = ((size_t)(b0 + um) * TC + tt) * 512 + uch;
        float xv0 = h2f(xg[xr]);
        float xv1 = h2f(xg[xr + 128]);
        float xv2 = h2f(xg[xr + 256]);
        float xv3 = h2f(xg[xr + 384]);

        // in-loop pin: asm "writes" Wf each step -> reload from memory is illegal
        asm volatile("" : "+v"(Wf[0][0]), "+v"(Wf[0][1]), "+v"(Wf[0][2]), "+v"(Wf[0][3]),
                          "+v"(Wf[1][0]), "+v"(Wf[1][1]), "+v"(Wf[1][2]), "+v"(Wf[1][3]),
                          "+v"(Wf[2][0]), "+v"(Wf[2][1]), "+v"(Wf[2][2]), "+v"(Wf[2][3]),
                          "+v"(Wf[3][0]), "+v"(Wf[3][1]), "+v"(Wf[3][2]), "+v"(Wf[3][3]));

        bf16x8 Af[4];
#pragma unroll
        for (int kt = 0; kt < 4; kt++)
            Af[kt] = *(const bf16x8*)((const char*)h_lds + abase + ((kt * 64 + akoff) ^ aswz));

        f32x4 acc[4];
#pragma unroll
        for (int q = 0; q < 4; q++) {
            f32x4 a = {0.f, 0.f, 0.f, 0.f};
#pragma unroll
            for (int kt = 0; kt < 4; kt++)
                a = __builtin_amdgcn_mfma_f32_16x16x32_bf16(Af[kt], Wf[q][kt], a, 0, 0, 0);
            acc[q] = a;
        }

        if (kg == 0) {
            const int chw = w * 16 + lr;
#pragma unroll
            for (int q = 0; q < 4; q++)
#pragma unroll
                for (int r = 0; r < 4; r++)
                    pre[q * 512 + r * 128 + chw] = acc[q][r];
        }
        __syncthreads();

        // full-wave update: 1 gate-quad per thread
        float pi = pre[0 * 512 + um * 128 + uch] + xv0;
        float pf = pre[1 * 512 + um * 128 + uch] + xv1;
        float pg = pre[2 * 512 + um * 128 + uch] + xv2;
        float po = pre[3 * 512 + um * 128 + uch] + xv3;
        float iv = sigm(pi), fv = sigm(pf), gv = tanhfast(pg), ov = sigm(po);
        c_reg = fv * c_reg + iv * gv;
        float hv = ov * tanhfast(c_reg);
        h_keep = hv;
        short hb16 = f2bf(hv);
        *(short*)((char*)h_lds + um * 256 + ((uch * 2) ^ (um << 4))) = hb16;
        if (WRITE_H)
            hout[((size_t)(b0 + um) * TC + tt) * 128 + uch] = (ushort_t)hb16;
        __syncthreads();
    }

    hs[(size_t)(b0 + um) * 128 + uch] = h_keep;
    cs[(size_t)(b0 + um) * 128 + uch] = c_reg;
}

template<int WRITE_H>
__global__ __launch_bounds__(512, 2)
void lstm_scan(const ushort_t* __restrict__ xg, const float* __restrict__ whh,
               float* __restrict__ hs, float* __restrict__ cs,
               ushort_t* __restrict__ hout, int TC)
{
    scan_body<WRITE_H>(xg, whh, hs, cs, hout, TC, blockIdx.x);
}

// blocks 0-127: layer-0 chunk c (writes h0c); 128-255: layer-1 chunk c-1
__global__ __launch_bounds__(512, 2)
void lstm_scan_dual(const ushort_t* __restrict__ xg0, const float* __restrict__ whh0,
                    float* __restrict__ h0s, float* __restrict__ c0s,
                    ushort_t* __restrict__ hout,
                    const ushort_t* __restrict__ xg1, const float* __restrict__ whh1,
                    float* __restrict__ h1s, float* __restrict__ c1s, int TC)
{
    if (blockIdx.x < 128)
        scan_body<1>(xg0, whh0, h0s, c0s, hout, TC, blockIdx.x);
    else
        scan_body<0>(xg1, whh1, h1s, c1s, nullptr, TC, blockIdx.x - 128);
}

// ---------------- head ---------------------------------------------------------------
__global__ __launch_bounds__(256, 2)
void head_k(const float* __restrict__ h1s, const float* __restrict__ W1,
            const float* __restrict__ b1, const float* __restrict__ W2,
            const float* __restrict__ b2, float* __restrict__ out)
{
    __shared__ float hrow[128];
    __shared__ float y1[256];
    const int b = blockIdx.x;
    const int tid = threadIdx.x;
    if (tid < 128) hrow[tid] = h1s[(size_t)b * 128 + tid];
    __syncthreads();
    {
        float acc = b1[tid];
        const float4* wp = (const float4*)(W1 + (size_t)tid * 128);
        const float4* hp = (const float4*)hrow;
#pragma unroll 8
        for (int q = 0; q < 32; q++) {
            float4 wv = wp[q]; float4 hv = hp[q];
            acc += wv.x * hv.x + wv.y * hv.y + wv.z * hv.z + wv.w * hv.w;
        }
        y1[tid] = celu1(acc);
    }
    __syncthreads();
    if (tid < 32) {
        float acc = b2[tid];
        const float4* wp = (const float4*)(W2 + (size_t)tid * 256);
        const float4* yp = (const float4*)y1;
#pragma unroll 8
        for (int q = 0; q < 64; q++) {
            float4 wv = wp[q]; float4 yv = yp[q];
            acc += wv.x * yv.x + wv.y * yv.y + wv.z * yv.z + wv.w * yv.w;
        }
        out[(size_t)b * 32 + tid] = celu1(acc);
    }
}

extern "C" void kernel_launch(void* const* d_in, const int* in_sizes, int n_in,
                              void* d_out, int out_size, void* d_ws, size_t ws_size,
                              hipStream_t stream)
{
    const float* x    = (const float*)d_in[0];
    const float* Wih0 = (const float*)d_in[1];
    const float* Whh0 = (const float*)d_in[2];
    const float* bih0 = (const float*)d_in[3];
    const float* bhh0 = (const float*)d_in[4];
    const float* Wih1 = (const float*)d_in[5];
    const float* Whh1 = (const float*)d_in[6];
    const float* bih1 = (const float*)d_in[7];
    const float* bhh1 = (const float*)d_in[8];
    const float* W1   = (const float*)d_in[9];
    const float* b1   = (const float*)d_in[10];
    const float* W2   = (const float*)d_in[11];
    const float* b2   = (const float*)d_in[12];
    float* out = (float*)d_out;

    // workspace: xg0, xg1 (fp16), h0c (bf16), 4 fp32 state arrays
    int TC = 128;
    while (TC > 8) {
        size_t need = 2ull * 512 * TC * 512 * 2 + (size_t)512 * TC * 128 * 2
                    + 4ull * 512 * 128 * 4;
        if (need <= ws_size) break;
        TC >>= 1;
    }

    ushort_t* xg0 = (ushort_t*)d_ws;
    ushort_t* xg1 = xg0 + (size_t)512 * TC * 512;
    ushort_t* h0c = xg1 + (size_t)512 * TC * 512;
    float* st  = (float*)(h0c + (size_t)512 * TC * 128);
    float* h0s = st;
    float* c0s = st + 512 * 128;
    float* h1s = st + 2 * 512 * 128;
    float* c1s = st + 3 * 512 * 128;

    hipMemsetAsync(st, 0, (size_t)4 * 512 * 128 * 4, stream);          // h,c = 0
    hipMemsetAsync(out + 16384, 0, (size_t)131072 * 4, stream);        // hidden_init = 0

    const int NC = 1024 / TC;
    dim3 g1((unsigned)(512 * TC / 128), 4, 1);
    dim3 g2((unsigned)(512 * TC / 128), 4, 2);

    gemm_pair<1><<<g1, 256, 0, stream>>>(x, Wih0, bih0, bhh0, xg0, 0,
                                         nullptr, Wih1, bih1, bhh1, xg1, TC);
    lstm_scan<1><<<128, 512, 0, stream>>>(xg0, Whh0, h0s, c0s, h0c, TC);
    for (int c = 1; c < NC; c++) {
        gemm_pair<0><<<g2, 256, 0, stream>>>(x, Wih0, bih0, bhh0, xg0, c * TC,
                                             h0c, Wih1, bih1, bhh1, xg1, TC);
        lstm_scan_dual<<<256, 512, 0, stream>>>(xg0, Whh0, h0s, c0s, h0c,
                                                xg1, Whh1, h1s, c1s, TC);
    }
    gemm_pair<2><<<g1, 256, 0, stream>>>(x, Wih0, bih0, bhh0, xg0, 0,
                                         h0c, Wih1, bih1, bhh1, xg1, TC);
    lstm_scan<0><<<128, 512, 0, stream>>>(xg1, Whh1, h1s, c1s, nullptr, TC);

    head_k<<<512, 256, 0, stream>>>(h1s, W1, b1, W2, b2, out);
}